// Round 3
// baseline (3610.970 us; speedup 1.0000x reference)
//
#include <hip/hip_runtime.h>
#include <hip/hip_bf16.h>
#include <math.h>

// TrueHopfieldLayer: HIDDEN=512, B=4, S=2048, 5 iters, thresh 1e-4.
// Round 9: eliminate the LDS staging round-trip in attention entirely.
// Round 8 post-mortem: ~7,000 of 18,000 cy/kt went through the LDS pipe
// (staging writes + fragment reads + 19% bank-conflict cycles) behind 10
// barriers/kt. But each warp's B-fragments (K rows 32s+l16, V rows
// 256s+64c+16nt+l16) are warp-private: load them global->VGPR directly at
// fragment addresses (16B bf16x8 loads). No staging LDS, no conflicts, and
// only 2 barriers/kt (around softmax). Sibling-warp duplicate reads hit L1
// (chunk working set = 32KB = L1). MFMA order identical to round 8 ->
// numerics unchanged. LDS drops 125KB -> ~52KB.
#define HH 512
#define BB 4
#define SS 2048
#define NN (BB*SS)
#define SCALE_F 0.04419417382415922f     // 1/sqrt(512)
#define THRESH 1e-4f
#define CTL_FLOATS 1024

typedef __attribute__((ext_vector_type(8))) short bf16x8;
typedef __attribute__((ext_vector_type(4))) float f32x4;

struct Ctl { float sum_d; float sum_o; int iters; int conv; int cur; int bf[10]; };

__device__ __forceinline__ float b2f(unsigned short u) {
    union { unsigned int i; float f; } c; c.i = ((unsigned int)u) << 16; return c.f;
}
__device__ __forceinline__ unsigned short f2b(float f) {
    unsigned int x = __float_as_uint(f);
    unsigned int r = (x + 0x7FFFu + ((x >> 16) & 1u)) >> 16;   // RNE
    return (unsigned short)r;
}
__device__ __forceinline__ void splitf(float x, unsigned short& h, unsigned short& l) {
    h = f2b(x);
    l = f2b(x - b2f(h));
}
__device__ __forceinline__ f32x4 MF(bf16x8 a, bf16x8 b, f32x4 c) {
    return __builtin_amdgcn_mfma_f32_16x16x32_bf16(a, b, c, 0, 0, 0);
}

// barrier that drains only LDS ops; global loads stay in flight
#define FBAR() do { \
    asm volatile("s_waitcnt lgkmcnt(0)" ::: "memory"); \
    __builtin_amdgcn_s_barrier(); \
    asm volatile("" ::: "memory"); \
} while (0)

// ---------- dtype detection (proven) ----------
__global__ __launch_bounds__(256) void detect_dtypes(
        const void* p0, const void* p1, const void* p2, const void* p3, const void* p4,
        const void* p5, const void* p6, const void* p7, const void* p8, Ctl* sc)
{
    const void* ps[9] = {p0,p1,p2,p3,p4,p5,p6,p7,p8};
    const int   ns[9] = {NN*HH, HH*HH, HH, HH*HH, HH, HH*HH, HH, HH*HH, HH};
    const int i = blockIdx.x;
    const unsigned short* u = (const unsigned short*)ps[i];
    const int n = ns[i] < 4096 ? ns[i] : 4096;
    __shared__ int cnt;
    if (threadIdx.x == 0) cnt = 0;
    __syncthreads();
    int c = 0;
    for (int j = threadIdx.x; j < n; j += 256) {
        const int e = (u[j] >> 7) & 0xFF;
        if (e < 32 || e >= 224) ++c;
    }
    if (c) atomicAdd(&cnt, c);
    __syncthreads();
    if (threadIdx.x == 0) sc->bf[i] = (cnt * 16 < n) ? 1 : 0;
}

__global__ __launch_bounds__(64) void init_flags(Ctl* sc) {
    if (threadIdx.x == 0) {
        sc->iters = 0; sc->conv = 0; sc->cur = 0; sc->sum_d = 0.f; sc->sum_o = 0.f;
        int any = 0;
        for (int i = 0; i < 9; ++i) any |= sc->bf[i];
        sc->bf[9] = any;
    }
}

// ---------- MFMA GEMM: C = X @ W^T + bias ----------
// mode 0: fp32 out (Q->state). mode 1: external out (X = state[cur] fp32 when xIdx==-2).
// mode 3: K -> KH,KL row-major + KTH,KTL transposed ([b][h][s]) planes.
// mode 4: V -> transposed planes into dead state buffer buf[1^cur].
__global__ __launch_bounds__(256) void mfma_gemm(
    const void* __restrict__ Xv, int xIdx,
    const void* __restrict__ Wv, int wIdx,
    const void* __restrict__ Bv, int bIdx,
    float* __restrict__ outF, void* __restrict__ outExt,
    unsigned short* __restrict__ pKH, unsigned short* __restrict__ pKL,
    unsigned short* __restrict__ pKTH, unsigned short* __restrict__ pKTL,
    float* __restrict__ S0w, float* __restrict__ S1w,
    int mode, const Ctl* __restrict__ sc)
{
    __shared__ unsigned short Xh[64][72], Xl[64][72], Wh[64][72], Wl[64][72];
    const int tid = threadIdx.x;
    const int cur = sc->cur;
    const void* Xp = (xIdx == -2) ? (const void*)(cur ? S1w : S0w) : Xv;
    const bool xbf = (xIdx >= 0) && (sc->bf[xIdx] != 0);
    const bool wbf = (sc->bf[wIdx] != 0);
    const bool bbf = (sc->bf[bIdx] != 0);
    const bool obf = (mode == 1) && (sc->bf[9] != 0);
    const bool xs = !xbf, ws = !wbf;

    const int m0 = blockIdx.x * 64, n0 = blockIdx.y * 64;
    const int lane = tid & 63, w = tid >> 6;
    const int mi = w & 1, ni = w >> 1;
    const int quad = lane >> 4, l16 = lane & 15;
    const int srow = tid >> 2, skb = (tid & 3) * 16;

    f32x4 acc[2][2];
    #pragma unroll
    for (int a = 0; a < 2; ++a)
        #pragma unroll
        for (int bq = 0; bq < 2; ++bq) acc[a][bq] = (f32x4){0.f, 0.f, 0.f, 0.f};

    for (int kc = 0; kc < HH; kc += 64) {
        __syncthreads();
        {
            float v[16];
            if (xbf) {
                const unsigned short* p = (const unsigned short*)Xp + (size_t)(m0 + srow)*HH + kc + skb;
                #pragma unroll
                for (int i = 0; i < 4; ++i) {
                    ushort4 t = *(const ushort4*)(p + 4*i);
                    v[4*i]=b2f(t.x); v[4*i+1]=b2f(t.y); v[4*i+2]=b2f(t.z); v[4*i+3]=b2f(t.w);
                }
            } else {
                const float* p = (const float*)Xp + (size_t)(m0 + srow)*HH + kc + skb;
                #pragma unroll
                for (int i = 0; i < 4; ++i) {
                    float4 t = *(const float4*)(p + 4*i);
                    v[4*i]=t.x; v[4*i+1]=t.y; v[4*i+2]=t.z; v[4*i+3]=t.w;
                }
            }
            #pragma unroll
            for (int i = 0; i < 4; ++i) {
                unsigned short h[4], l[4];
                #pragma unroll
                for (int j = 0; j < 4; ++j) splitf(v[4*i+j], h[j], l[j]);
                *(ushort4*)&Xh[srow][skb + 4*i] = make_ushort4(h[0], h[1], h[2], h[3]);
                if (xs) *(ushort4*)&Xl[srow][skb + 4*i] = make_ushort4(l[0], l[1], l[2], l[3]);
            }
        }
        {
            float v[16];
            if (wbf) {
                const unsigned short* p = (const unsigned short*)Wv + (size_t)(n0 + srow)*HH + kc + skb;
                #pragma unroll
                for (int i = 0; i < 4; ++i) {
                    ushort4 t = *(const ushort4*)(p + 4*i);
                    v[4*i]=b2f(t.x); v[4*i+1]=b2f(t.y); v[4*i+2]=b2f(t.z); v[4*i+3]=b2f(t.w);
                }
            } else {
                const float* p = (const float*)Wv + (size_t)(n0 + srow)*HH + kc + skb;
                #pragma unroll
                for (int i = 0; i < 4; ++i) {
                    float4 t = *(const float4*)(p + 4*i);
                    v[4*i]=t.x; v[4*i+1]=t.y; v[4*i+2]=t.z; v[4*i+3]=t.w;
                }
            }
            #pragma unroll
            for (int i = 0; i < 4; ++i) {
                unsigned short h[4], l[4];
                #pragma unroll
                for (int j = 0; j < 4; ++j) splitf(v[4*i+j], h[j], l[j]);
                *(ushort4*)&Wh[srow][skb + 4*i] = make_ushort4(h[0], h[1], h[2], h[3]);
                if (ws) *(ushort4*)&Wl[srow][skb + 4*i] = make_ushort4(l[0], l[1], l[2], l[3]);
            }
        }
        __syncthreads();
        #pragma unroll
        for (int d = 0; d < 2; ++d) {
            const int kl = 32*d + quad*8;
            #pragma unroll
            for (int mt = 0; mt < 2; ++mt) {
                const int xr = 32*mi + 16*mt + l16;
                bf16x8 ahx = *(const bf16x8*)&Xh[xr][kl];
                bf16x8 alx;
                if (xs) alx = *(const bf16x8*)&Xl[xr][kl];
                #pragma unroll
                for (int nt = 0; nt < 2; ++nt) {
                    const int wr = 32*ni + 16*nt + l16;
                    bf16x8 bh = *(const bf16x8*)&Wh[wr][kl];
                    acc[mt][nt] = MF(ahx, bh, acc[mt][nt]);
                    if (xs) acc[mt][nt] = MF(alx, bh, acc[mt][nt]);
                    if (ws) {
                        bf16x8 bl = *(const bf16x8*)&Wl[wr][kl];
                        acc[mt][nt] = MF(ahx, bl, acc[mt][nt]);
                    }
                }
            }
        }
    }
    unsigned short* vtH = nullptr;
    if (mode == 4) { vtH = (unsigned short*)(cur ? S0w : S1w); }
    #pragma unroll
    for (int nt = 0; nt < 2; ++nt) {
        const int col = n0 + 32*ni + 16*nt + l16;
        const float bv = bbf ? b2f(((const unsigned short*)Bv)[col]) : ((const float*)Bv)[col];
        #pragma unroll
        for (int mt = 0; mt < 2; ++mt)
            #pragma unroll
            for (int e = 0; e < 4; ++e) {
                const int row = m0 + 32*mi + 16*mt + quad*4 + e;
                const float vv = acc[mt][nt][e] + bv;
                const size_t idx = (size_t)row*HH + col;
                if (mode == 0) outF[idx] = vv;
                else if (mode == 1) {
                    if (obf) ((unsigned short*)outExt)[idx] = f2b(vv);
                    else     ((float*)outExt)[idx] = vv;
                } else {
                    unsigned short h, l; splitf(vv, h, l);
                    const size_t t = ((size_t)(row >> 11) * HH + col) * SS + (row & 2047);
                    if (mode == 3) {
                        pKH[idx] = h; pKL[idx] = l;
                        pKTH[t] = h;  pKTL[t] = l;
                    } else {                       // mode 4: V transposed planes
                        vtH[t] = h; vtH[(size_t)NN*HH + t] = l;
                    }
                }
            }
    }
}

// ---------- MFMA flash attention, split-bf16, direct-global B fragments ----------
template<bool FINAL>
__global__ __launch_bounds__(256, 1) void mfma_attn(
    float* __restrict__ S0w, float* __restrict__ S1w,
    const unsigned short* __restrict__ KH, const unsigned short* __restrict__ KL,
    const unsigned short* __restrict__ KTH, const unsigned short* __restrict__ KTL,
    Ctl* sc)
{
    if constexpr (!FINAL) { if (sc->conv) return; }
    const int cur = sc->cur;
    float* Scur = cur ? S1w : S0w;
    float* Out  = FINAL ? Scur : (cur ? S0w : S1w);
    const unsigned short* VTH = FINAL ? (const unsigned short*)(cur ? S0w : S1w) : KTH;
    const unsigned short* VTL = FINAL ? (VTH + (size_t)NN*HH) : KTL;

    __shared__ __align__(16) unsigned short SHl[32*520];
    __shared__ __align__(16) unsigned short Pth[32*72], Ptl[32*72];
    __shared__ __align__(16) float Sld[32*68];
    __shared__ __align__(16) float mld[32], lld[32], ald[32];
    __shared__ float redd[4], redo[4];

    const int tid = threadIdx.x;
    const int lane = tid & 63, w = tid >> 6;
    const int quad = lane >> 4, l16 = lane & 15;
    const int r = w & 1, s = w >> 1;

    const int bid = blockIdx.x;
    const int e8 = bid & 7;
    const int b = e8 >> 1;
    const int q0 = 32 * ((bid >> 3) + 32 * (e8 & 1));

    const size_t bSSHH = (size_t)b * SS * HH;
    const size_t bHHSS = (size_t)b * HH * SS;

    // ---- load state tile: hi frags to regs, lo plane to LDS ----
    bf16x8 ah[16];
    {
        const float* Qr = Scur + ((size_t)b*SS + q0 + 16*r + l16) * HH + quad*8;
        #pragma unroll
        for (int f = 0; f < 16; ++f) {
            float4 v0 = *(const float4*)(Qr + 32*f);
            float4 v1 = *(const float4*)(Qr + 32*f + 4);
            unsigned short h[8], l[8];
            splitf(v0.x,h[0],l[0]); splitf(v0.y,h[1],l[1]); splitf(v0.z,h[2],l[2]); splitf(v0.w,h[3],l[3]);
            splitf(v1.x,h[4],l[4]); splitf(v1.y,h[5],l[5]); splitf(v1.z,h[6],l[6]); splitf(v1.w,h[7],l[7]);
            bf16x8 af;
            #pragma unroll
            for (int j = 0; j < 8; ++j) af[j] = (short)h[j];
            ah[f] = af;
            if (s == 0) {
                unsigned short* d = &SHl[(16*r + l16)*520 + 32*f + quad*8];
                *(ushort4*)(d)     = make_ushort4(l[0], l[1], l[2], l[3]);
                *(ushort4*)(d + 4) = make_ushort4(l[4], l[5], l[6], l[7]);
            }
        }
        if (tid < 32) { mld[tid] = -INFINITY; lld[tid] = 0.f; }
    }
    FBAR();   // SHl + mld/lld visible to all waves

    f32x4 O[16];
    #pragma unroll
    for (int i = 0; i < 16; ++i) O[i] = (f32x4){0.f, 0.f, 0.f, 0.f};

    const int shlbase = (16*r + l16)*520 + quad*8;

    for (int kt = 0; kt < SS/64; ++kt) {
        // 4 accumulator chains (even/odd k-step) for MFMA-latency ILP
        f32x4 sA0 = (f32x4){0.f,0.f,0.f,0.f}, sB0 = (f32x4){0.f,0.f,0.f,0.f};
        f32x4 sA1 = (f32x4){0.f,0.f,0.f,0.f}, sB1 = (f32x4){0.f,0.f,0.f,0.f};
        // ---- scores: K fragments direct from global (rows 32s+l16, +16) ----
        {
            const unsigned short* KHp = KH + bSSHH + (size_t)(kt*64 + 32*s + l16)*HH + quad*8;
            const unsigned short* KLp = KL + bSSHH + (size_t)(kt*64 + 32*s + l16)*HH + quad*8;
            #pragma unroll
            for (int c = 0; c < 4; ++c) {
                bf16x8 bh0v[4], bl0v[4], bh1v[4], bl1v[4];
                #pragma unroll
                for (int kf = 0; kf < 4; ++kf) {
                    const int gb = c*128 + kf*32;
                    bh0v[kf] = *(const bf16x8*)(KHp + gb);
                    bl0v[kf] = *(const bf16x8*)(KLp + gb);
                    bh1v[kf] = *(const bf16x8*)(KHp + 16*HH + gb);
                    bl1v[kf] = *(const bf16x8*)(KLp + 16*HH + gb);
                }
                #pragma unroll
                for (int kf = 0; kf < 4; ++kf) {
                    bf16x8 alf = *(const bf16x8*)&SHl[shlbase + c*128 + kf*32];
                    const bf16x8 a = ah[c*4 + kf];
                    if (kf & 1) {
                        sB0 = MF(a, bh0v[kf], sB0); sB0 = MF(alf, bh0v[kf], sB0); sB0 = MF(a, bl0v[kf], sB0);
                        sB1 = MF(a, bh1v[kf], sB1); sB1 = MF(alf, bh1v[kf], sB1); sB1 = MF(a, bl1v[kf], sB1);
                    } else {
                        sA0 = MF(a, bh0v[kf], sA0); sA0 = MF(alf, bh0v[kf], sA0); sA0 = MF(a, bl0v[kf], sA0);
                        sA1 = MF(a, bh1v[kf], sA1); sA1 = MF(alf, bh1v[kf], sA1); sA1 = MF(a, bl1v[kf], sA1);
                    }
                }
            }
        }
        f32x4 sacc0 = sA0 + sB0;
        f32x4 sacc1 = sA1 + sB1;
        #pragma unroll
        for (int e = 0; e < 4; ++e) {
            Sld[(16*r + quad*4 + e)*68 + 32*s + l16]      = sacc0[e] * SCALE_F;
            Sld[(16*r + quad*4 + e)*68 + 32*s + 16 + l16] = sacc1[e] * SCALE_F;
        }
        FBAR();
        // ---- online softmax: 8 threads/row over 64 keys ----
        {
            const int row = tid >> 3, sg = tid & 7;
            const float* sr = Sld + row*68 + sg*8;
            float4 x0 = *(const float4*)(sr);
            float4 x1 = *(const float4*)(sr + 4);
            float mt = fmaxf(fmaxf(fmaxf(x0.x,x0.y), fmaxf(x0.z,x0.w)),
                             fmaxf(fmaxf(x1.x,x1.y), fmaxf(x1.z,x1.w)));
            #pragma unroll
            for (int mk = 1; mk < 8; mk <<= 1) mt = fmaxf(mt, __shfl_xor(mt, mk, 8));
            const float mprev = mld[row];
            const float mnew = fmaxf(mprev, mt);
            float p[8];
            p[0]=__expf(x0.x-mnew); p[1]=__expf(x0.y-mnew); p[2]=__expf(x0.z-mnew); p[3]=__expf(x0.w-mnew);
            p[4]=__expf(x1.x-mnew); p[5]=__expf(x1.y-mnew); p[6]=__expf(x1.z-mnew); p[7]=__expf(x1.w-mnew);
            float ps = p[0]+p[1]+p[2]+p[3]+p[4]+p[5]+p[6]+p[7];
            #pragma unroll
            for (int mk = 1; mk < 8; mk <<= 1) ps += __shfl_xor(ps, mk, 8);
            const float alpha = __expf(mprev - mnew);
            if (sg == 0) { mld[row] = mnew; lld[row] = lld[row]*alpha + ps; ald[row] = alpha; }
            unsigned short h[8], l[8];
            #pragma unroll
            for (int i = 0; i < 8; ++i) splitf(p[i], h[i], l[i]);
            unsigned short* dh = &Pth[row*72 + sg*8];
            unsigned short* dl = &Ptl[row*72 + sg*8];
            *(ushort4*)(dh)     = make_ushort4(h[0],h[1],h[2],h[3]);
            *(ushort4*)(dh + 4) = make_ushort4(h[4],h[5],h[6],h[7]);
            *(ushort4*)(dl)     = make_ushort4(l[0],l[1],l[2],l[3]);
            *(ushort4*)(dl + 4) = make_ushort4(l[4],l[5],l[6],l[7]);
        }
        FBAR();
        // ---- rescale O, load P frags ----
        {
            const float4 av = *(const float4*)&ald[16*r + 4*quad];
            const float a4[4] = {av.x, av.y, av.z, av.w};
            #pragma unroll
            for (int i = 0; i < 16; ++i)
                #pragma unroll
                for (int e = 0; e < 4; ++e) O[i][e] *= a4[e];
        }
        bf16x8 pah[2], pal[2];
        #pragma unroll
        for (int kf = 0; kf < 2; ++kf) {
            pah[kf] = *(const bf16x8*)&Pth[(16*r + l16)*72 + kf*32 + quad*8];
            pal[kf] = *(const bf16x8*)&Ptl[(16*r + l16)*72 + kf*32 + quad*8];
        }
        // ---- PV: V fragments direct from global (rows 256s+64c+16nt+l16) ----
        #pragma unroll
        for (int c = 0; c < 4; ++c) {
            bf16x8 vh[4][2], vl[4][2];
            #pragma unroll
            for (int nt = 0; nt < 4; ++nt)
                #pragma unroll
                for (int kf = 0; kf < 2; ++kf) {
                    const size_t g = bHHSS + (size_t)(256*s + 64*c + 16*nt + l16)*SS
                                   + (size_t)kt*64 + kf*32 + quad*8;
                    vh[nt][kf] = *(const bf16x8*)(VTH + g);
                    vl[nt][kf] = *(const bf16x8*)(VTL + g);
                }
            #pragma unroll
            for (int nt = 0; nt < 4; ++nt)
                #pragma unroll
                for (int kf = 0; kf < 2; ++kf) {
                    O[c*4+nt] = MF(pah[kf], vh[nt][kf], O[c*4+nt]);
                    O[c*4+nt] = MF(pal[kf], vh[nt][kf], O[c*4+nt]);
                    O[c*4+nt] = MF(pah[kf], vl[nt][kf], O[c*4+nt]);
                }
        }
    }
    // ---- epilogue ----
    const float4 lv = *(const float4*)&lld[16*r + 4*quad];
    const float inv[4] = {1.f/lv.x, 1.f/lv.y, 1.f/lv.z, 1.f/lv.w};
    float pd = 0.f, po2 = 0.f;
    #pragma unroll
    for (int c = 0; c < 4; ++c)
        #pragma unroll
        for (int nt = 0; nt < 4; ++nt)
            #pragma unroll
            for (int e = 0; e < 4; ++e) {
                const int row = q0 + 16*r + quad*4 + e;
                const int col = 256*s + 64*c + 16*nt + l16;
                const float nv = O[c*4+nt][e] * inv[e];
                const size_t idx = (size_t)b*SS*HH + (size_t)row*HH + col;
                if constexpr (!FINAL) {
                    const float old = Scur[idx];
                    const float d = nv - old;
                    pd += d*d; po2 += old*old;
                }
                Out[idx] = nv;
            }
    if constexpr (!FINAL) {
        #pragma unroll
        for (int mk = 1; mk < 64; mk <<= 1) {
            pd  += __shfl_xor(pd, mk, 64);
            po2 += __shfl_xor(po2, mk, 64);
        }
        if (lane == 0) { redd[w] = pd; redo[w] = po2; }
        __syncthreads();
        if (tid == 0) {
            atomicAdd(&sc->sum_d, redd[0] + redd[1] + redd[2] + redd[3]);
            atomicAdd(&sc->sum_o, redo[0] + redo[1] + redo[2] + redo[3]);
        }
    }
}

__global__ __launch_bounds__(64) void flag_update(Ctl* sc) {
    if (threadIdx.x != 0) return;
    if (sc->conv) return;
    sc->cur ^= 1;
    sc->iters += 1;
    const float delta = sqrtf(sc->sum_d) / (sqrtf(sc->sum_o) + 1e-8f);
    if (delta < THRESH) sc->conv = 1;
    sc->sum_d = 0.f; sc->sum_o = 0.f;
}

__global__ __launch_bounds__(64) void write_scalars(const Ctl* sc, void* outv) {
    if (threadIdx.x != 0) return;
    if (sc->bf[9]) {
        unsigned short* o = (unsigned short*)outv;
        o[(size_t)NN*HH]     = f2b((float)sc->iters);
        o[(size_t)NN*HH + 1] = f2b(sc->conv ? 1.0f : 0.0f);
    } else {
        float* o = (float*)outv;
        o[(size_t)NN*HH]     = (float)sc->iters;
        o[(size_t)NN*HH + 1] = sc->conv ? 1.0f : 0.0f;
    }
}

extern "C" void kernel_launch(void* const* d_in, const int* in_sizes, int n_in,
                              void* d_out, int out_size, void* d_ws, size_t ws_size,
                              hipStream_t stream)
{
    const void* x  = d_in[0];
    const void* Wq = d_in[1];
    const void* bq = d_in[2];
    const void* Wk = d_in[3];
    const void* bk = d_in[4];
    const void* Wv = d_in[5];
    const void* bv = d_in[6];
    const void* Wo = d_in[7];
    const void* bo = d_in[8];

    Ctl* sc = (Ctl*)d_ws;
    float* S0 = (float*)d_ws + CTL_FLOATS;                 // [NN,HH] fp32 state ping
    float* S1 = S0 + (size_t)NN*HH;                        // [NN,HH] fp32 state pong / VT planes
    unsigned short* KH  = (unsigned short*)(S1 + (size_t)NN*HH);
    unsigned short* KL  = KH  + (size_t)NN*HH;
    unsigned short* KTH = KL  + (size_t)NN*HH;
    unsigned short* KTL = KTH + (size_t)NN*HH;             // total ~67.1 MB (proven)

    const dim3 ggrid(NN/64, HH/64);   // 128 x 8
    const int  agrid = 256;           // 1D, XCD-swizzled

    detect_dtypes<<<9, 256, 0, stream>>>(x, Wq, bq, Wk, bk, Wv, bv, Wo, bo, sc);
    init_flags<<<1, 64, 0, stream>>>(sc);

    // Q projection -> S0 (fp32)
    mfma_gemm<<<ggrid, 256, 0, stream>>>(x, 0, Wq, 1, bq, 2, S0, nullptr,
                                         nullptr, nullptr, nullptr, nullptr, S0, S1, 0, sc);
    // K projection -> KH/KL + transposed KTH/KTL
    mfma_gemm<<<ggrid, 256, 0, stream>>>(x, 0, Wk, 3, bk, 4, nullptr, nullptr,
                                         KH, KL, KTH, KTL, S0, S1, 3, sc);

    for (int it = 0; it < 5; ++it) {
        mfma_attn<false><<<agrid, 256, 0, stream>>>(S0, S1, KH, KL, KTH, KTL, sc);
        flag_update<<<1, 64, 0, stream>>>(sc);
    }

    // V projection -> transposed planes into the dead state buffer buf[1^cur]
    mfma_gemm<<<ggrid, 256, 0, stream>>>(x, 0, Wv, 5, bv, 6, nullptr, nullptr,
                                         nullptr, nullptr, nullptr, nullptr, S0, S1, 4, sc);
    // Final readout attention (in-place on buf[cur], V from VT planes)
    mfma_attn<true><<<agrid, 256, 0, stream>>>(S0, S1, KH, KL, KTH, KTL, sc);
    // Output projection from buf[cur]
    mfma_gemm<<<ggrid, 256, 0, stream>>>(nullptr, -2, Wo, 7, bo, 8, nullptr, d_out,
                                         nullptr, nullptr, nullptr, nullptr, S0, S1, 1, sc);
    if (out_size >= (int)((size_t)NN*HH + 2))
        write_scalars<<<1, 64, 0, stream>>>(sc, d_out);
}

// Round 4
// 1276.664 us; speedup vs baseline: 2.8284x; 2.8284x over previous
//
#include <hip/hip_runtime.h>
#include <hip/hip_bf16.h>
#include <math.h>

// TrueHopfieldLayer: HIDDEN=512, B=4, S=2048, 5 iters, thresh 1e-4.
// Round 10: round-8 structure (best: 240us attn) + 2 waves/SIMD.
// Round 9 post-mortem: direct-global B-frags exposed L2 latency before every
// MFMA (585us) -- reverted. Round 8's residual cost is barrier-serialized
// phase latency that 1 wave/SIMD cannot overlap. This round: same grid (256
// blocks = 1/CU), same LDS layout/dbuf/ring/FBAR, but 512 threads = 8 waves
// = 2 waves/SIMD. Warp roles: r=w&1 (16-row half), s=w>>1 (0..3): scores one
// 16-key tile/warp; PV 32-col slice per chunk (O[8], -32 VGPR); staging per
// thread halved (ring = 8 named uint4); softmax 16 threads/row. PV chunk c
// stages hid rows {128g+32c+j}, read at LDS row 32s+16nt+l16 -> out col
// 128s+32c+16nt+l16. MFMA sequence per output unchanged -> numerics same.
#define HH 512
#define BB 4
#define SS 2048
#define NN (BB*SS)
#define SCALE_F 0.04419417382415922f     // 1/sqrt(512)
#define THRESH 1e-4f
#define CTL_FLOATS 1024

typedef __attribute__((ext_vector_type(8))) short bf16x8;
typedef __attribute__((ext_vector_type(4))) float f32x4;

struct Ctl { float sum_d; float sum_o; int iters; int conv; int cur; int bf[10]; };

__device__ __forceinline__ float b2f(unsigned short u) {
    union { unsigned int i; float f; } c; c.i = ((unsigned int)u) << 16; return c.f;
}
__device__ __forceinline__ unsigned short f2b(float f) {
    unsigned int x = __float_as_uint(f);
    unsigned int r = (x + 0x7FFFu + ((x >> 16) & 1u)) >> 16;   // RNE
    return (unsigned short)r;
}
__device__ __forceinline__ void splitf(float x, unsigned short& h, unsigned short& l) {
    h = f2b(x);
    l = f2b(x - b2f(h));
}
__device__ __forceinline__ f32x4 MF(bf16x8 a, bf16x8 b, f32x4 c) {
    return __builtin_amdgcn_mfma_f32_16x16x32_bf16(a, b, c, 0, 0, 0);
}

// barrier that drains only LDS ops; prefetched global loads stay in flight
#define FBAR() do { \
    asm volatile("s_waitcnt lgkmcnt(0)" ::: "memory"); \
    __builtin_amdgcn_s_barrier(); \
    asm volatile("" ::: "memory"); \
} while (0)

// Prefetch ring ops on NAMED registers (R = Ra or Rb). 2 uint4 per plane.
#define LD4(R, ph, pl) do { \
    const unsigned short* _ph = (ph); const unsigned short* _pl = (pl); \
    R##0 = *(const uint4*)(_ph); R##1 = *(const uint4*)(_ph + 8); \
    R##2 = *(const uint4*)(_pl); R##3 = *(const uint4*)(_pl + 8); \
} while (0)
#define ST4(dh, dl, R) do { \
    unsigned short* _dh = (dh); unsigned short* _dl = (dl); \
    *(uint4*)(_dh) = R##0; *(uint4*)(_dh + 8) = R##1; \
    *(uint4*)(_dl) = R##2; *(uint4*)(_dl + 8) = R##3; \
} while (0)

// ---------- dtype detection (proven) ----------
__global__ __launch_bounds__(256) void detect_dtypes(
        const void* p0, const void* p1, const void* p2, const void* p3, const void* p4,
        const void* p5, const void* p6, const void* p7, const void* p8, Ctl* sc)
{
    const void* ps[9] = {p0,p1,p2,p3,p4,p5,p6,p7,p8};
    const int   ns[9] = {NN*HH, HH*HH, HH, HH*HH, HH, HH*HH, HH, HH*HH, HH};
    const int i = blockIdx.x;
    const unsigned short* u = (const unsigned short*)ps[i];
    const int n = ns[i] < 4096 ? ns[i] : 4096;
    __shared__ int cnt;
    if (threadIdx.x == 0) cnt = 0;
    __syncthreads();
    int c = 0;
    for (int j = threadIdx.x; j < n; j += 256) {
        const int e = (u[j] >> 7) & 0xFF;
        if (e < 32 || e >= 224) ++c;
    }
    if (c) atomicAdd(&cnt, c);
    __syncthreads();
    if (threadIdx.x == 0) sc->bf[i] = (cnt * 16 < n) ? 1 : 0;
}

__global__ __launch_bounds__(64) void init_flags(Ctl* sc) {
    if (threadIdx.x == 0) {
        sc->iters = 0; sc->conv = 0; sc->cur = 0; sc->sum_d = 0.f; sc->sum_o = 0.f;
        int any = 0;
        for (int i = 0; i < 9; ++i) any |= sc->bf[i];
        sc->bf[9] = any;
    }
}

// ---------- MFMA GEMM: C = X @ W^T + bias ----------
// mode 0: fp32 out (Q->state). mode 1: external out (X = state[cur] fp32 when xIdx==-2).
// mode 3: K -> KH,KL row-major + KTH,KTL transposed ([b][h][s]) planes.
// mode 4: V -> transposed planes into dead state buffer buf[1^cur].
__global__ __launch_bounds__(256) void mfma_gemm(
    const void* __restrict__ Xv, int xIdx,
    const void* __restrict__ Wv, int wIdx,
    const void* __restrict__ Bv, int bIdx,
    float* __restrict__ outF, void* __restrict__ outExt,
    unsigned short* __restrict__ pKH, unsigned short* __restrict__ pKL,
    unsigned short* __restrict__ pKTH, unsigned short* __restrict__ pKTL,
    float* __restrict__ S0w, float* __restrict__ S1w,
    int mode, const Ctl* __restrict__ sc)
{
    __shared__ unsigned short Xh[64][72], Xl[64][72], Wh[64][72], Wl[64][72];
    const int tid = threadIdx.x;
    const int cur = sc->cur;
    const void* Xp = (xIdx == -2) ? (const void*)(cur ? S1w : S0w) : Xv;
    const bool xbf = (xIdx >= 0) && (sc->bf[xIdx] != 0);
    const bool wbf = (sc->bf[wIdx] != 0);
    const bool bbf = (sc->bf[bIdx] != 0);
    const bool obf = (mode == 1) && (sc->bf[9] != 0);
    const bool xs = !xbf, ws = !wbf;

    const int m0 = blockIdx.x * 64, n0 = blockIdx.y * 64;
    const int lane = tid & 63, w = tid >> 6;
    const int mi = w & 1, ni = w >> 1;
    const int quad = lane >> 4, l16 = lane & 15;
    const int srow = tid >> 2, skb = (tid & 3) * 16;

    f32x4 acc[2][2];
    #pragma unroll
    for (int a = 0; a < 2; ++a)
        #pragma unroll
        for (int bq = 0; bq < 2; ++bq) acc[a][bq] = (f32x4){0.f, 0.f, 0.f, 0.f};

    for (int kc = 0; kc < HH; kc += 64) {
        __syncthreads();
        {
            float v[16];
            if (xbf) {
                const unsigned short* p = (const unsigned short*)Xp + (size_t)(m0 + srow)*HH + kc + skb;
                #pragma unroll
                for (int i = 0; i < 4; ++i) {
                    ushort4 t = *(const ushort4*)(p + 4*i);
                    v[4*i]=b2f(t.x); v[4*i+1]=b2f(t.y); v[4*i+2]=b2f(t.z); v[4*i+3]=b2f(t.w);
                }
            } else {
                const float* p = (const float*)Xp + (size_t)(m0 + srow)*HH + kc + skb;
                #pragma unroll
                for (int i = 0; i < 4; ++i) {
                    float4 t = *(const float4*)(p + 4*i);
                    v[4*i]=t.x; v[4*i+1]=t.y; v[4*i+2]=t.z; v[4*i+3]=t.w;
                }
            }
            #pragma unroll
            for (int i = 0; i < 4; ++i) {
                unsigned short h[4], l[4];
                #pragma unroll
                for (int j = 0; j < 4; ++j) splitf(v[4*i+j], h[j], l[j]);
                *(ushort4*)&Xh[srow][skb + 4*i] = make_ushort4(h[0], h[1], h[2], h[3]);
                if (xs) *(ushort4*)&Xl[srow][skb + 4*i] = make_ushort4(l[0], l[1], l[2], l[3]);
            }
        }
        {
            float v[16];
            if (wbf) {
                const unsigned short* p = (const unsigned short*)Wv + (size_t)(n0 + srow)*HH + kc + skb;
                #pragma unroll
                for (int i = 0; i < 4; ++i) {
                    ushort4 t = *(const ushort4*)(p + 4*i);
                    v[4*i]=b2f(t.x); v[4*i+1]=b2f(t.y); v[4*i+2]=b2f(t.z); v[4*i+3]=b2f(t.w);
                }
            } else {
                const float* p = (const float*)Wv + (size_t)(n0 + srow)*HH + kc + skb;
                #pragma unroll
                for (int i = 0; i < 4; ++i) {
                    float4 t = *(const float4*)(p + 4*i);
                    v[4*i]=t.x; v[4*i+1]=t.y; v[4*i+2]=t.z; v[4*i+3]=t.w;
                }
            }
            #pragma unroll
            for (int i = 0; i < 4; ++i) {
                unsigned short h[4], l[4];
                #pragma unroll
                for (int j = 0; j < 4; ++j) splitf(v[4*i+j], h[j], l[j]);
                *(ushort4*)&Wh[srow][skb + 4*i] = make_ushort4(h[0], h[1], h[2], h[3]);
                if (ws) *(ushort4*)&Wl[srow][skb + 4*i] = make_ushort4(l[0], l[1], l[2], l[3]);
            }
        }
        __syncthreads();
        #pragma unroll
        for (int d = 0; d < 2; ++d) {
            const int kl = 32*d + quad*8;
            #pragma unroll
            for (int mt = 0; mt < 2; ++mt) {
                const int xr = 32*mi + 16*mt + l16;
                bf16x8 ahx = *(const bf16x8*)&Xh[xr][kl];
                bf16x8 alx;
                if (xs) alx = *(const bf16x8*)&Xl[xr][kl];
                #pragma unroll
                for (int nt = 0; nt < 2; ++nt) {
                    const int wr = 32*ni + 16*nt + l16;
                    bf16x8 bh = *(const bf16x8*)&Wh[wr][kl];
                    acc[mt][nt] = MF(ahx, bh, acc[mt][nt]);
                    if (xs) acc[mt][nt] = MF(alx, bh, acc[mt][nt]);
                    if (ws) {
                        bf16x8 bl = *(const bf16x8*)&Wl[wr][kl];
                        acc[mt][nt] = MF(ahx, bl, acc[mt][nt]);
                    }
                }
            }
        }
    }
    unsigned short* vtH = nullptr;
    if (mode == 4) { vtH = (unsigned short*)(cur ? S0w : S1w); }
    #pragma unroll
    for (int nt = 0; nt < 2; ++nt) {
        const int col = n0 + 32*ni + 16*nt + l16;
        const float bv = bbf ? b2f(((const unsigned short*)Bv)[col]) : ((const float*)Bv)[col];
        #pragma unroll
        for (int mt = 0; mt < 2; ++mt)
            #pragma unroll
            for (int e = 0; e < 4; ++e) {
                const int row = m0 + 32*mi + 16*mt + quad*4 + e;
                const float vv = acc[mt][nt][e] + bv;
                const size_t idx = (size_t)row*HH + col;
                if (mode == 0) outF[idx] = vv;
                else if (mode == 1) {
                    if (obf) ((unsigned short*)outExt)[idx] = f2b(vv);
                    else     ((float*)outExt)[idx] = vv;
                } else {
                    unsigned short h, l; splitf(vv, h, l);
                    const size_t t = ((size_t)(row >> 11) * HH + col) * SS + (row & 2047);
                    if (mode == 3) {
                        pKH[idx] = h; pKL[idx] = l;
                        pKTH[t] = h;  pKTL[t] = l;
                    } else {                       // mode 4: V transposed planes
                        vtH[t] = h; vtH[(size_t)NN*HH + t] = l;
                    }
                }
            }
    }
}

// ---------- MFMA flash attention, split-bf16, 8 waves (2/SIMD) ----------
template<bool FINAL>
__global__ __launch_bounds__(512, 2) void mfma_attn(
    float* __restrict__ S0w, float* __restrict__ S1w,
    const unsigned short* __restrict__ KH, const unsigned short* __restrict__ KL,
    const unsigned short* __restrict__ KTH, const unsigned short* __restrict__ KTL,
    Ctl* sc)
{
    if constexpr (!FINAL) { if (sc->conv) return; }
    const int cur = sc->cur;
    float* Scur = cur ? S1w : S0w;
    float* Out  = FINAL ? Scur : (cur ? S0w : S1w);
    const unsigned short* VTH = FINAL ? (const unsigned short*)(cur ? S0w : S1w) : KTH;
    const unsigned short* VTL = FINAL ? (VTH + (size_t)NN*HH) : KTL;

    // double-buffered staging: per buffer max(64*136*2, 128*72*2) ushorts = 18432
    __shared__ __align__(16) unsigned short UB0[18432];
    __shared__ __align__(16) unsigned short UB1[18432];
    __shared__ __align__(16) unsigned short SHl[32*520];
    __shared__ __align__(16) unsigned short Pth[32*72], Ptl[32*72];
    __shared__ __align__(16) float Sld[32*68];
    __shared__ __align__(16) float mld[32], lld[32], ald[32];
    __shared__ float redd[8], redo[8];

    const int tid = threadIdx.x;
    const int lane = tid & 63, w = tid >> 6;          // w in 0..7
    const int quad = lane >> 4, l16 = lane & 15;
    const int r = w & 1, s = w >> 1;                  // r: 16-row half, s: 0..3

    const int bid = blockIdx.x;
    const int e8 = bid & 7;
    const int b = e8 >> 1;
    const int q0 = 32 * ((bid >> 3) + 32 * (e8 & 1));

    const size_t bSSHH = (size_t)b * SS * HH;
    const size_t bHHSS = (size_t)b * HH * SS;

    const int key = tid >> 3, hs = (tid & 7) * 16;    // scores staging: 64 rows x 8x16
    const int rw = tid >> 2, k1 = (tid & 3) * 16;     // PV staging: 128 rows x 4x16

    const unsigned short* pSH = KH + bSSHH + (size_t)key*HH + hs;
    const unsigned short* pSL = KL + bSSHH + (size_t)key*HH + hs;
    // PV chunk c stages hid rows 128*(rw>>5) + 32*c + (rw&31)
    const size_t vbase = bHHSS + (size_t)(128*(rw >> 5) + (rw & 31))*SS + k1;
    const unsigned short* pVH = VTH + vbase;
    const unsigned short* pVL = VTL + vbase;

    // 2-deep prefetch ring: 8 NAMED uint4 registers
    uint4 Ra0, Ra1, Ra2, Ra3;
    uint4 Rb0, Rb1, Rb2, Rb3;
    LD4(Ra, pSH, pSL);              // S(kt=0, c=0)
    LD4(Rb, pSH + 128, pSL + 128);  // S(kt=0, c=1)

    // ---- load state tile: hi frags to regs, lo plane to LDS ----
    bf16x8 ah[16];
    {
        const float* Qr = Scur + ((size_t)b*SS + q0 + 16*r + l16) * HH + quad*8;
        #pragma unroll
        for (int f = 0; f < 16; ++f) {
            float4 v0 = *(const float4*)(Qr + 32*f);
            float4 v1 = *(const float4*)(Qr + 32*f + 4);
            unsigned short h[8], l[8];
            splitf(v0.x,h[0],l[0]); splitf(v0.y,h[1],l[1]); splitf(v0.z,h[2],l[2]); splitf(v0.w,h[3],l[3]);
            splitf(v1.x,h[4],l[4]); splitf(v1.y,h[5],l[5]); splitf(v1.z,h[6],l[6]); splitf(v1.w,h[7],l[7]);
            bf16x8 af;
            #pragma unroll
            for (int j = 0; j < 8; ++j) af[j] = (short)h[j];
            ah[f] = af;
            if (s == 0) {
                unsigned short* d = &SHl[(16*r + l16)*520 + 32*f + quad*8];
                *(ushort4*)(d)     = make_ushort4(l[0], l[1], l[2], l[3]);
                *(ushort4*)(d + 4) = make_ushort4(l[4], l[5], l[6], l[7]);
            }
        }
        if (tid < 32) { mld[tid] = -INFINITY; lld[tid] = 0.f; }
    }

    f32x4 O[8];
    #pragma unroll
    for (int i = 0; i < 8; ++i) O[i] = (f32x4){0.f, 0.f, 0.f, 0.f};

    const int shlbase = (16*r + l16)*520 + quad*8;

    for (int kt = 0; kt < SS/64; ++kt) {
        const size_t so = (size_t)kt*64*HH;               // scores row offset
        const size_t po = (size_t)kt*64;                  // PV col offset
        // 2 accumulator chains (even/odd kf) for MFMA-latency ILP
        f32x4 sA = (f32x4){0.f,0.f,0.f,0.f}, sB = (f32x4){0.f,0.f,0.f,0.f};
        // ---- scores: 4 hid-chunks of 128, dbuf + prefetch(+2) ----
        #pragma unroll
        for (int c = 0; c < 4; ++c) {
            unsigned short* ub = (c & 1) ? UB1 : UB0;     // compile-time select
            if ((c & 1) == 0) {
                ST4(ub + key*136 + hs, ub + 8704 + key*136 + hs, Ra);
                if (c == 0) LD4(Ra, pSH + so + 2*128, pSL + so + 2*128);
                else        LD4(Ra, pVH + po, pVL + po);                      // c==2: PV chunk 0
            } else {
                ST4(ub + key*136 + hs, ub + 8704 + key*136 + hs, Rb);
                if (c == 1) LD4(Rb, pSH + so + 3*128, pSL + so + 3*128);
                else        LD4(Rb, pVH + (size_t)32*SS + po, pVL + (size_t)32*SS + po);  // c==3: PV chunk 1
            }
            FBAR();
            #pragma unroll
            for (int kf = 0; kf < 4; ++kf) {
                bf16x8 alf = *(const bf16x8*)&SHl[shlbase + c*128 + kf*32];
                const int c0 = kf*32 + quad*8;
                bf16x8 bh = *(const bf16x8*)&ub[(16*s + l16)*136 + c0];
                bf16x8 bl = *(const bf16x8*)&ub[8704 + (16*s + l16)*136 + c0];
                const bf16x8 a = ah[c*4 + kf];
                if (kf & 1) {
                    sB = MF(a, bh, sB); sB = MF(alf, bh, sB); sB = MF(a, bl, sB);
                } else {
                    sA = MF(a, bh, sA); sA = MF(alf, bh, sA); sA = MF(a, bl, sA);
                }
            }
        }
        f32x4 sacc = sA + sB;
        #pragma unroll
        for (int e = 0; e < 4; ++e)
            Sld[(16*r + quad*4 + e)*68 + 16*s + l16] = sacc[e] * SCALE_F;
        FBAR();
        // ---- online softmax: 16 threads/row over 64 keys ----
        {
            const int row = tid >> 4, sg = tid & 15;
            const float* sr = Sld + row*68 + sg*4;
            float4 x0 = *(const float4*)(sr);
            float mt = fmaxf(fmaxf(x0.x, x0.y), fmaxf(x0.z, x0.w));
            #pragma unroll
            for (int mk = 1; mk < 16; mk <<= 1) mt = fmaxf(mt, __shfl_xor(mt, mk, 16));
            const float mprev = mld[row];
            const float mnew = fmaxf(mprev, mt);
            float p[4];
            p[0]=__expf(x0.x-mnew); p[1]=__expf(x0.y-mnew); p[2]=__expf(x0.z-mnew); p[3]=__expf(x0.w-mnew);
            float ps = p[0]+p[1]+p[2]+p[3];
            #pragma unroll
            for (int mk = 1; mk < 16; mk <<= 1) ps += __shfl_xor(ps, mk, 16);
            const float alpha = __expf(mprev - mnew);
            if (sg == 0) { mld[row] = mnew; lld[row] = lld[row]*alpha + ps; ald[row] = alpha; }
            unsigned short h[4], l[4];
            #pragma unroll
            for (int i = 0; i < 4; ++i) splitf(p[i], h[i], l[i]);
            *(ushort4*)&Pth[row*72 + sg*4] = make_ushort4(h[0],h[1],h[2],h[3]);
            *(ushort4*)&Ptl[row*72 + sg*4] = make_ushort4(l[0],l[1],l[2],l[3]);
        }
        FBAR();
        // ---- rescale O, load P frags ----
        {
            const float4 av = *(const float4*)&ald[16*r + 4*quad];
            const float a4[4] = {av.x, av.y, av.z, av.w};
            #pragma unroll
            for (int i = 0; i < 8; ++i)
                #pragma unroll
                for (int e = 0; e < 4; ++e) O[i][e] *= a4[e];
        }
        bf16x8 pah[2], pal[2];
        #pragma unroll
        for (int kf = 0; kf < 2; ++kf) {
            pah[kf] = *(const bf16x8*)&Pth[(16*r + l16)*72 + kf*32 + quad*8];
            pal[kf] = *(const bf16x8*)&Ptl[(16*r + l16)*72 + kf*32 + quad*8];
        }
        // ---- PV: 4 chunks of 32 hid-cols/warp, dbuf + prefetch(+2) ----
        #pragma unroll
        for (int c = 0; c < 4; ++c) {
            unsigned short* ub = (c & 1) ? UB1 : UB0;     // compile-time select
            if ((c & 1) == 0) {
                ST4(ub + rw*72 + k1, ub + 9216 + rw*72 + k1, Ra);
                if (c == 0)             LD4(Ra, pVH + (size_t)64*SS + po, pVL + (size_t)64*SS + po);
                else if (kt+1 < SS/64)  LD4(Ra, pSH + so + (size_t)64*HH,
                                             pSL + so + (size_t)64*HH);       // next-kt S chunk 0
            } else {
                ST4(ub + rw*72 + k1, ub + 9216 + rw*72 + k1, Rb);
                if (c == 1)             LD4(Rb, pVH + (size_t)96*SS + po, pVL + (size_t)96*SS + po);
                else if (kt+1 < SS/64)  LD4(Rb, pSH + so + (size_t)64*HH + 128,
                                             pSL + so + (size_t)64*HH + 128); // next-kt S chunk 1
            }
            FBAR();
            #pragma unroll
            for (int nt = 0; nt < 2; ++nt) {
                const int rb = (32*s + 16*nt + l16)*72;
                #pragma unroll
                for (int kf = 0; kf < 2; ++kf) {
                    bf16x8 bh = *(const bf16x8*)&ub[rb + kf*32 + quad*8];
                    bf16x8 bl = *(const bf16x8*)&ub[9216 + rb + kf*32 + quad*8];
                    O[c*2+nt] = MF(pah[kf], bh, O[c*2+nt]);
                    O[c*2+nt] = MF(pal[kf], bh, O[c*2+nt]);
                    O[c*2+nt] = MF(pah[kf], bl, O[c*2+nt]);
                }
            }
        }
    }
    // ---- epilogue ----
    const float4 lv = *(const float4*)&lld[16*r + 4*quad];
    const float inv[4] = {1.f/lv.x, 1.f/lv.y, 1.f/lv.z, 1.f/lv.w};
    float pd = 0.f, po2 = 0.f;
    #pragma unroll
    for (int c = 0; c < 4; ++c)
        #pragma unroll
        for (int nt = 0; nt < 2; ++nt)
            #pragma unroll
            for (int e = 0; e < 4; ++e) {
                const int row = q0 + 16*r + quad*4 + e;
                const int col = 128*s + 32*c + 16*nt + l16;
                const float nv = O[c*2+nt][e] * inv[e];
                const size_t idx = (size_t)b*SS*HH + (size_t)row*HH + col;
                if constexpr (!FINAL) {
                    const float old = Scur[idx];
                    const float d = nv - old;
                    pd += d*d; po2 += old*old;
                }
                Out[idx] = nv;
            }
    if constexpr (!FINAL) {
        #pragma unroll
        for (int mk = 1; mk < 64; mk <<= 1) {
            pd  += __shfl_xor(pd, mk, 64);
            po2 += __shfl_xor(po2, mk, 64);
        }
        if (lane == 0) { redd[w] = pd; redo[w] = po2; }
        __syncthreads();
        if (tid == 0) {
            float td = 0.f, to = 0.f;
            #pragma unroll
            for (int i = 0; i < 8; ++i) { td += redd[i]; to += redo[i]; }
            atomicAdd(&sc->sum_d, td);
            atomicAdd(&sc->sum_o, to);
        }
    }
}

__global__ __launch_bounds__(64) void flag_update(Ctl* sc) {
    if (threadIdx.x != 0) return;
    if (sc->conv) return;
    sc->cur ^= 1;
    sc->iters += 1;
    const float delta = sqrtf(sc->sum_d) / (sqrtf(sc->sum_o) + 1e-8f);
    if (delta < THRESH) sc->conv = 1;
    sc->sum_d = 0.f; sc->sum_o = 0.f;
}

__global__ __launch_bounds__(64) void write_scalars(const Ctl* sc, void* outv) {
    if (threadIdx.x != 0) return;
    if (sc->bf[9]) {
        unsigned short* o = (unsigned short*)outv;
        o[(size_t)NN*HH]     = f2b((float)sc->iters);
        o[(size_t)NN*HH + 1] = f2b(sc->conv ? 1.0f : 0.0f);
    } else {
        float* o = (float*)outv;
        o[(size_t)NN*HH]     = (float)sc->iters;
        o[(size_t)NN*HH + 1] = sc->conv ? 1.0f : 0.0f;
    }
}

extern "C" void kernel_launch(void* const* d_in, const int* in_sizes, int n_in,
                              void* d_out, int out_size, void* d_ws, size_t ws_size,
                              hipStream_t stream)
{
    const void* x  = d_in[0];
    const void* Wq = d_in[1];
    const void* bq = d_in[2];
    const void* Wk = d_in[3];
    const void* bk = d_in[4];
    const void* Wv = d_in[5];
    const void* bv = d_in[6];
    const void* Wo = d_in[7];
    const void* bo = d_in[8];

    Ctl* sc = (Ctl*)d_ws;
    float* S0 = (float*)d_ws + CTL_FLOATS;                 // [NN,HH] fp32 state ping
    float* S1 = S0 + (size_t)NN*HH;                        // [NN,HH] fp32 state pong / VT planes
    unsigned short* KH  = (unsigned short*)(S1 + (size_t)NN*HH);
    unsigned short* KL  = KH  + (size_t)NN*HH;
    unsigned short* KTH = KL  + (size_t)NN*HH;
    unsigned short* KTL = KTH + (size_t)NN*HH;             // total ~67.1 MB (proven)

    const dim3 ggrid(NN/64, HH/64);   // 128 x 8
    const int  agrid = 256;           // 1D, XCD-swizzled

    detect_dtypes<<<9, 256, 0, stream>>>(x, Wq, bq, Wk, bk, Wv, bv, Wo, bo, sc);
    init_flags<<<1, 64, 0, stream>>>(sc);

    // Q projection -> S0 (fp32)
    mfma_gemm<<<ggrid, 256, 0, stream>>>(x, 0, Wq, 1, bq, 2, S0, nullptr,
                                         nullptr, nullptr, nullptr, nullptr, S0, S1, 0, sc);
    // K projection -> KH/KL + transposed KTH/KTL
    mfma_gemm<<<ggrid, 256, 0, stream>>>(x, 0, Wk, 3, bk, 4, nullptr, nullptr,
                                         KH, KL, KTH, KTL, S0, S1, 3, sc);

    for (int it = 0; it < 5; ++it) {
        mfma_attn<false><<<agrid, 512, 0, stream>>>(S0, S1, KH, KL, KTH, KTL, sc);
        flag_update<<<1, 64, 0, stream>>>(sc);
    }

    // V projection -> transposed planes into the dead state buffer buf[1^cur]
    mfma_gemm<<<ggrid, 256, 0, stream>>>(x, 0, Wv, 5, bv, 6, nullptr, nullptr,
                                         nullptr, nullptr, nullptr, nullptr, S0, S1, 4, sc);
    // Final readout attention (in-place on buf[cur], V from VT planes)
    mfma_attn<true><<<agrid, 512, 0, stream>>>(S0, S1, KH, KL, KTH, KTL, sc);
    // Output projection from buf[cur]
    mfma_gemm<<<ggrid, 256, 0, stream>>>(nullptr, -2, Wo, 7, bo, 8, nullptr, d_out,
                                         nullptr, nullptr, nullptr, nullptr, S0, S1, 1, sc);
    if (out_size >= (int)((size_t)NN*HH + 2))
        write_scalars<<<1, 64, 0, stream>>>(sc, d_out);
}